// Round 8
// baseline (119.243 us; speedup 1.0000x reference)
//
#include <hip/hip_runtime.h>
#include <hip/hip_bf16.h>

// WaveNet single-output inference on MI355X — sparse-tree fused, packed-split v3.
// Only skip_sum[:, :, 8190] matters. Dependency set per layer is an arithmetic
// progression with stride = dilation/2; h_12 never needed.
// Kernel A: in_conv + layers 0-5 per block via exact-fit halo pyramid
//           (96->95->47->23->11->5->2) producing 2 compact h6 outputs.
// Kernel B: layers 6-11 + skip + f1/f2 head, one block per batch, all in LDS.
// v3 (perf): hi/lo bf16 split packed into ONE u32 per value = (hi | lo<<16).
// A packed u32 is two MFMA k-slots, so with prep-built B-arrays
//   B' = (h,h), B'' = (l,0):  A'.B' + A'.B'' = Ah.Bh + Al.Bh + Ah.Bl
// — same 3-product precision as before, but: half the LDS arrays/traffic,
// 1 ds_write_b32 per element (was 2x b16), native HW bf16 cvt (was 4-5 int ops),
// no per-layer weight staging/barrier, LDS 61->37 KB (4 blocks/CU).

typedef __attribute__((ext_vector_type(8))) short short8;
typedef __attribute__((ext_vector_type(4))) float f32x4;

#define TLAST  8190
#define BATCH  32

__device__ inline ushort bf16hi(float v) {
    union { __hip_bfloat16 b; ushort u; } c;
    c.b = __float2bfloat16(v);
    return c.u;
}
__device__ inline uint packsplit(float v) {
    const ushort h = bf16hi(v);
    const float hf = __uint_as_float((uint)h << 16);
    const ushort l = bf16hi(v - hf);
    return (uint)h | ((uint)l << 16);
}
__device__ inline float unpacksum(uint u) {
    return __uint_as_float(u << 16) + __uint_as_float(u & 0xffff0000u);
}
__device__ inline short8 as_s8(uint4 v) {
    union { uint4 u; short8 s; } c; c.u = v; return c.s;
}
__device__ inline int imin(int a, int b) { return a < b ? a : b; }

// ---------------------------------------------------------------- weight prep
// Packed-pair weights. Element e = ic + 32*tap (tap 0 = left tap t-d/2).
//   Wp1[l][n][e] = (h , h)  as u32 (h low, h high)
//   Wp2[l][n][e] = (lo, 0)
// Res: Wr1/Wr2[l][n][ic] same scheme.
__global__ __launch_bounds__(256) void wn_prep(
    const float* __restrict__ dil_w, const float* __restrict__ res_w,
    uint* __restrict__ Wp1, uint* __restrict__ Wp2,
    uint* __restrict__ Wr1, uint* __restrict__ Wr2)
{
    const int idx = blockIdx.x * 256 + threadIdx.x;
    if (idx < 12 * 4096) {
        const int l = idx >> 12, rem = idx & 4095, n = rem >> 6, e = rem & 63;
        const int tap = e >> 5, ic = e & 31;
        const float v = dil_w[((size_t)l * 64 + n) * 64 + 2 * ic + tap];
        const ushort h  = bf16hi(v);
        const ushort lo = bf16hi(v - __uint_as_float((uint)h << 16));
        Wp1[idx] = (uint)h | ((uint)h << 16);
        Wp2[idx] = (uint)lo;
    } else if (idx < 12 * 4096 + 12 * 1024) {
        const int j = idx - 12 * 4096;
        const float v = res_w[j];
        const ushort h  = bf16hi(v);
        const ushort lo = bf16hi(v - __uint_as_float((uint)h << 16));
        Wr1[j] = (uint)h | ((uint)h << 16);
        Wr2[j] = (uint)lo;
    }
}

// ---------------------------------------------------------------- phase A
// One block = one (chunk, batch): produces h6 at t = t6a, t6a+32.
// Dense window H0: t in [t6a-31, t6a+64] (96 rows). Exact-fit pyramid.
// H rows: 32 packed u32 channels, stride 36 (16B-aligned rows).
__global__ __launch_bounds__(256) void wn_fuseA(
    const float* __restrict__ x, const float* __restrict__ in_w,
    const float* __restrict__ in_b,
    const uint* __restrict__ Wp1, const uint* __restrict__ Wp2,
    const uint* __restrict__ Wr1, const uint* __restrict__ Wr2,
    const float* __restrict__ dil_b, const float* __restrict__ res_b,
    uint* __restrict__ c6, float* __restrict__ gTL)
{
    __shared__ __align__(16) uint HA[96 * 36];
    __shared__ __align__(16) uint HB[96 * 36];      // xs overlays (dead after in_conv)
    __shared__ __align__(16) uint sG[4][16 * 36];
    float* xs = (float*)HB;                         // 96*20 floats = 7.7 KB

    const int tid  = threadIdx.x;
    const int cc   = blockIdx.x, b = blockIdx.y;
    const int lane = tid & 63, w = tid >> 6;
    const int nl   = lane & 15, o = lane >> 4;
    const int t6a  = 6174 + cc * 64;
    const int a0   = t6a - 31;                      // global t of H0 row 0
    const short8 z8 = {0,0,0,0,0,0,0,0};

    // ---- stage x (96 pos x 16 ch, fp32)
    for (int i = tid; i < 384; i += 256) {
        const int p = i >> 2, c4 = (i & 3) * 4;
        const int t = a0 + p;
        float4 v = make_float4(0.f, 0.f, 0.f, 0.f);
        if (t <= 8191) v = *(const float4*)&x[((size_t)b * 8192 + t) * 16 + c4];
        *(float4*)&xs[p * 20 + c4] = v;
    }
    __syncthreads();

    // ---- in_conv -> HA (packed split)
    {
        const int c = tid & 31, pg = tid >> 5;
        float wr[16];
        #pragma unroll
        for (int f = 0; f < 16; ++f) wr[f] = in_w[c * 16 + f];
        const float bias = in_b[c];
        #pragma unroll
        for (int q = 0; q < 12; ++q) {
            const int p = pg + 8 * q;               // 0..95
            float acc = bias;
            #pragma unroll
            for (int f4 = 0; f4 < 4; ++f4) {
                const float4 xv = *(const float4*)&xs[p * 20 + f4 * 4];
                acc += wr[f4*4+0]*xv.x + wr[f4*4+1]*xv.y
                     + wr[f4*4+2]*xv.z + wr[f4*4+3]*xv.w;
            }
            HA[p * 36 + c] = packsplit(acc);
        }
    }
    __syncthreads();   // xs dead; HB free for l=0 output

    for (int l = 0; l < 6; ++l) {
        const uint* Hi = (l & 1) ? HB : HA;
        uint*       Ho = (l & 1) ? HA : HB;
        const int nIn  = (l == 0) ? 96 : (192 >> l) - 1;
        const int nOut = (192 >> (l + 1)) - 1;      // 95,47,23,11,5,2
        const int nT   = (nOut + 15) >> 4;
        const int sO   = 1 << l;
        const int aO   = a0 + sO - 1;
        const int bOff = (l == 0) ? 1 : (sO >> 1);
        const int rmx  = (l == 0) ? 8191 : TLAST;

        const uint* pd1 = Wp1 + (size_t)l * 4096;
        const uint* pd2 = Wp2 + (size_t)l * 4096;
        const uint* pr1 = Wr1 + (size_t)l * 1024;
        const uint* pr2 = Wr2 + (size_t)l * 1024;

        float dbg[2], dbf[2], rbv[2];
        #pragma unroll
        for (int nt = 0; nt < 2; ++nt) {
            dbg[nt] = dil_b[l * 64 + nl + 16 * nt];
            dbf[nt] = dil_b[l * 64 + nl + 16 * nt + 32];
            rbv[nt] = res_b[l * 32 + nl + 16 * nt];
        }

        for (int tt = w; tt < nT; tt += 4) {
            const int joF = tt * 16 + nl;
            const int j0 = imin((l == 0) ? joF : 2 * joF, nIn - 1);
            const int j1 = imin((l == 0) ? joF + 1 : 2 * joF + 2, nIn - 1);
            const bool zB = (aO + joF * sO + bOff) > rmx;

            // ---- A fragments: per (tap, kt) one b128 of 4 packed u32
            short8 a[2][2];
            #pragma unroll
            for (int kt = 0; kt < 2; ++kt) {
                a[0][kt] = as_s8(*(const uint4*)&Hi[j0 * 36 + kt * 16 + 4 * o]);
                a[1][kt] = zB ? z8
                              : as_s8(*(const uint4*)&Hi[j1 * 36 + kt * 16 + 4 * o]);
            }

            // ---- gate/filt GEMM: 32 MFMAs (2 tap x 2 kt x 4 nt x 2 arrays)
            f32x4 acc[4] = {{0,0,0,0},{0,0,0,0},{0,0,0,0},{0,0,0,0}};
            #pragma unroll
            for (int tap = 0; tap < 2; ++tap)
                #pragma unroll
                for (int kt = 0; kt < 2; ++kt) {
                    const int eb = tap * 32 + kt * 16 + 4 * o;
                    #pragma unroll
                    for (int nt = 0; nt < 4; ++nt) {
                        const int n = nl + 16 * nt;
                        const short8 b1 = as_s8(*(const uint4*)&pd1[n * 64 + eb]);
                        const short8 b2 = as_s8(*(const uint4*)&pd2[n * 64 + eb]);
                        acc[nt] = __builtin_amdgcn_mfma_f32_16x16x32_bf16(a[tap][kt], b1, acc[nt], 0, 0, 0);
                        acc[nt] = __builtin_amdgcn_mfma_f32_16x16x32_bf16(a[tap][kt], b2, acc[nt], 0, 0, 0);
                    }
                }

            // ---- activation + per-wave packed G + gTL capture
            #pragma unroll
            for (int nt = 0; nt < 2; ++nt)
                #pragma unroll
                for (int r = 0; r < 4; ++r) {
                    const float gate = acc[nt][r]     + dbg[nt];
                    const float filt = acc[nt + 2][r] + dbf[nt];
                    const float sg = 1.f / (1.f + __expf(-gate));
                    const float th = 2.f / (1.f + __expf(-2.f * filt)) - 1.f;
                    const float g  = th * sg;
                    const int ml = 4 * o + r;
                    const int n  = nl + 16 * nt;
                    sG[w][ml * 36 + n] = packsplit(g);
                    const int joG = tt * 16 + ml;
                    if (joG < nOut && (aO + joG * sO) == TLAST)
                        gTL[((size_t)l * BATCH + b) * 32 + n] = g;
                }

            // ---- res GEMM: 8 MFMAs (same-wave LDS, no barrier)
            short8 gp[2];
            #pragma unroll
            for (int kt = 0; kt < 2; ++kt)
                gp[kt] = as_s8(*(const uint4*)&sG[w][nl * 36 + kt * 16 + 4 * o]);
            f32x4 accR[2] = {{0,0,0,0},{0,0,0,0}};
            #pragma unroll
            for (int kt = 0; kt < 2; ++kt) {
                const int eb = kt * 16 + 4 * o;
                #pragma unroll
                for (int nt = 0; nt < 2; ++nt) {
                    const int n = nl + 16 * nt;
                    const short8 r1 = as_s8(*(const uint4*)&pr1[n * 32 + eb]);
                    const short8 r2 = as_s8(*(const uint4*)&pr2[n * 32 + eb]);
                    accR[nt] = __builtin_amdgcn_mfma_f32_16x16x32_bf16(gp[kt], r1, accR[nt], 0, 0, 0);
                    accR[nt] = __builtin_amdgcn_mfma_f32_16x16x32_bf16(gp[kt], r2, accR[nt], 0, 0, 0);
                }
            }

            // ---- epilogue: + bias + residual (packed read), packed store
            #pragma unroll
            for (int nt = 0; nt < 2; ++nt)
                #pragma unroll
                for (int r = 0; r < 4; ++r) {
                    const int ml  = 4 * o + r;
                    const int joE = tt * 16 + ml;
                    const int jres = imin((l == 0) ? joE + 1 : 2 * joE + 1, nIn - 1);
                    const int n = nl + 16 * nt;
                    const float resv = unpacksum(Hi[jres * 36 + n]);
                    const float hv = accR[nt][r] + rbv[nt] + resv;
                    const uint pk = packsplit(hv);
                    Ho[joE * 36 + n] = pk;
                    if (l == 5 && joE < 2)
                        c6[((size_t)b * 64 + cc * 2 + joE) * 32 + n] = pk;
                }
        }
        __syncthreads();
    }
}

// ---------------------------------------------------------------- phase B
// One block per batch: layers 6-11 (compact, in LDS) + skip sum + f1/f2 head.
__global__ __launch_bounds__(256) void wn_fuseB(
    const uint* __restrict__ c6,
    const uint* __restrict__ Wp1, const uint* __restrict__ Wp2,
    const uint* __restrict__ Wr1, const uint* __restrict__ Wr2,
    const float* __restrict__ dil_b, const float* __restrict__ res_b,
    const float* __restrict__ gTL,
    const float* __restrict__ sw, const float* __restrict__ sb,
    const float* __restrict__ f1w, const float* __restrict__ f1b,
    const float* __restrict__ f2w, const float* __restrict__ f2b,
    float* __restrict__ out)
{
    __shared__ __align__(16) uint HA[64 * 36];
    __shared__ __align__(16) uint HB[32 * 36];
    __shared__ __align__(16) uint sG[4][16 * 36];
    __shared__ float gcap[6][33];
    __shared__ float ss[32], z1[32];

    const int tid  = threadIdx.x, b = blockIdx.x;
    const int lane = tid & 63, w = tid >> 6;
    const int nl   = lane & 15, o = lane >> 4;
    const short8 z8 = {0,0,0,0,0,0,0,0};

    // ---- stage c6 (64 rows x 32 packed u32), uint4 chunks
    for (int i = tid; i < 512; i += 256) {
        const int row = i >> 3, c4 = (i & 7) * 4;
        *(uint4*)&HA[row * 36 + c4] =
            *(const uint4*)&c6[((size_t)b * 64 + row) * 32 + c4];
    }
    __syncthreads();

    for (int ll = 0; ll < 6; ++ll) {
        const int l = ll + 6;
        const uint* Hi = (ll & 1) ? HB : HA;
        uint*       Ho = (ll & 1) ? HA : HB;
        const int nIn  = 64 >> ll;
        const int nOut = 32 >> ll;
        const int nT   = (nOut + 15) >> 4;
        const int sO   = 64 << ll;
        const int aO   = 6142 + sO;
        const int bOff = sO >> 1;

        const uint* pd1 = Wp1 + (size_t)l * 4096;
        const uint* pd2 = Wp2 + (size_t)l * 4096;
        const uint* pr1 = Wr1 + (size_t)l * 1024;
        const uint* pr2 = Wr2 + (size_t)l * 1024;

        float dbg[2], dbf[2], rbv[2];
        #pragma unroll
        for (int nt = 0; nt < 2; ++nt) {
            dbg[nt] = dil_b[l * 64 + nl + 16 * nt];
            dbf[nt] = dil_b[l * 64 + nl + 16 * nt + 32];
            rbv[nt] = res_b[l * 32 + nl + 16 * nt];
        }

        for (int tt = w; tt < nT; tt += 4) {
            const int joF = tt * 16 + nl;
            const int j0 = imin(2 * joF, nIn - 1);
            const int j1 = imin(2 * joF + 2, nIn - 1);
            const bool zB = (aO + joF * sO + bOff) > TLAST;

            short8 a[2][2];
            #pragma unroll
            for (int kt = 0; kt < 2; ++kt) {
                a[0][kt] = as_s8(*(const uint4*)&Hi[j0 * 36 + kt * 16 + 4 * o]);
                a[1][kt] = zB ? z8
                              : as_s8(*(const uint4*)&Hi[j1 * 36 + kt * 16 + 4 * o]);
            }

            f32x4 acc[4] = {{0,0,0,0},{0,0,0,0},{0,0,0,0},{0,0,0,0}};
            #pragma unroll
            for (int tap = 0; tap < 2; ++tap)
                #pragma unroll
                for (int kt = 0; kt < 2; ++kt) {
                    const int eb = tap * 32 + kt * 16 + 4 * o;
                    #pragma unroll
                    for (int nt = 0; nt < 4; ++nt) {
                        const int n = nl + 16 * nt;
                        const short8 b1 = as_s8(*(const uint4*)&pd1[n * 64 + eb]);
                        const short8 b2 = as_s8(*(const uint4*)&pd2[n * 64 + eb]);
                        acc[nt] = __builtin_amdgcn_mfma_f32_16x16x32_bf16(a[tap][kt], b1, acc[nt], 0, 0, 0);
                        acc[nt] = __builtin_amdgcn_mfma_f32_16x16x32_bf16(a[tap][kt], b2, acc[nt], 0, 0, 0);
                    }
                }

            #pragma unroll
            for (int nt = 0; nt < 2; ++nt)
                #pragma unroll
                for (int r = 0; r < 4; ++r) {
                    const float gate = acc[nt][r]     + dbg[nt];
                    const float filt = acc[nt + 2][r] + dbf[nt];
                    const float sg = 1.f / (1.f + __expf(-gate));
                    const float th = 2.f / (1.f + __expf(-2.f * filt)) - 1.f;
                    const float g  = th * sg;
                    const int ml = 4 * o + r;
                    const int n  = nl + 16 * nt;
                    sG[w][ml * 36 + n] = packsplit(g);
                    const int joG = tt * 16 + ml;
                    if (joG < nOut && (aO + joG * sO) == TLAST)
                        gcap[ll][n] = g;
                }

            if (ll < 5) {
                short8 gp[2];
                #pragma unroll
                for (int kt = 0; kt < 2; ++kt)
                    gp[kt] = as_s8(*(const uint4*)&sG[w][nl * 36 + kt * 16 + 4 * o]);
                f32x4 accR[2] = {{0,0,0,0},{0,0,0,0}};
                #pragma unroll
                for (int kt = 0; kt < 2; ++kt) {
                    const int eb = kt * 16 + 4 * o;
                    #pragma unroll
                    for (int nt = 0; nt < 2; ++nt) {
                        const int n = nl + 16 * nt;
                        const short8 r1 = as_s8(*(const uint4*)&pr1[n * 32 + eb]);
                        const short8 r2 = as_s8(*(const uint4*)&pr2[n * 32 + eb]);
                        accR[nt] = __builtin_amdgcn_mfma_f32_16x16x32_bf16(gp[kt], r1, accR[nt], 0, 0, 0);
                        accR[nt] = __builtin_amdgcn_mfma_f32_16x16x32_bf16(gp[kt], r2, accR[nt], 0, 0, 0);
                    }
                }
                #pragma unroll
                for (int nt = 0; nt < 2; ++nt)
                    #pragma unroll
                    for (int r = 0; r < 4; ++r) {
                        const int ml  = 4 * o + r;
                        const int joE = tt * 16 + ml;
                        const int jres = imin(2 * joE + 1, nIn - 1);
                        const int n = nl + 16 * nt;
                        const float resv = unpacksum(Hi[jres * 36 + n]);
                        const float hv = accR[nt][r] + rbv[nt] + resv;
                        Ho[joE * 36 + n] = packsplit(hv);
                    }
            }
        }
        __syncthreads();
    }

    // ---- skip sum + head (per batch)
    if (tid < 32) {
        const int c = tid;
        float acc = 0.f;
        #pragma unroll
        for (int l2 = 0; l2 < 12; ++l2) {
            float a = sb[l2 * 32 + c];
            #pragma unroll
            for (int ic = 0; ic < 32; ++ic) {
                const float gv = (l2 < 6) ? gTL[((size_t)l2 * BATCH + b) * 32 + ic]
                                          : gcap[l2 - 6][ic];
                a += sw[l2 * 1024 + c * 32 + ic] * gv;
            }
            acc += a;
        }
        ss[c] = fmaxf(acc, 0.f);
    }
    __syncthreads();
    if (tid < 32) {
        float z = f1b[tid];
        #pragma unroll
        for (int ic = 0; ic < 32; ++ic) z += f1w[tid * 32 + ic] * ss[ic];
        z1[tid] = fmaxf(z, 0.f);
    }
    __syncthreads();
    if (tid == 0) {
        float o2 = f2b[0];
        #pragma unroll
        for (int ic = 0; ic < 32; ++ic) o2 += f2w[ic] * z1[ic];
        out[b] = o2;
    }
}

// ---------------------------------------------------------------- launch
extern "C" void kernel_launch(void* const* d_in, const int* in_sizes, int n_in,
                              void* d_out, int out_size, void* d_ws, size_t ws_size,
                              hipStream_t stream)
{
    const float* x      = (const float*)d_in[0];
    const float* in_w   = (const float*)d_in[1];
    const float* in_b   = (const float*)d_in[2];
    const float* dil_w  = (const float*)d_in[3];
    const float* dil_b  = (const float*)d_in[4];
    const float* skip_w = (const float*)d_in[5];
    const float* skip_b = (const float*)d_in[6];
    const float* res_w  = (const float*)d_in[7];
    const float* res_b  = (const float*)d_in[8];
    const float* f1_w   = (const float*)d_in[9];
    const float* f1_b   = (const float*)d_in[10];
    const float* f2_w   = (const float*)d_in[11];
    const float* f2_b   = (const float*)d_in[12];

    char* p = (char*)d_ws;
    uint* Wp1 = (uint*)p; p += 12 * 4096 * 4;
    uint* Wp2 = (uint*)p; p += 12 * 4096 * 4;
    uint* Wr1 = (uint*)p; p += 12 * 1024 * 4;
    uint* Wr2 = (uint*)p; p += 12 * 1024 * 4;
    uint* c6  = (uint*)p; p += 32 * 64 * 32 * 4;
    float* gTL = (float*)p;                    // [12][32][32]

    wn_prep<<<dim3((12 * 4096 + 12 * 1024 + 255) / 256), dim3(256), 0, stream>>>(
        dil_w, res_w, Wp1, Wp2, Wr1, Wr2);

    wn_fuseA<<<dim3(32, BATCH), dim3(256), 0, stream>>>(
        x, in_w, in_b, Wp1, Wp2, Wr1, Wr2, dil_b, res_b, c6, gTL);

    wn_fuseB<<<dim3(BATCH), dim3(256), 0, stream>>>(
        c6, Wp1, Wp2, Wr1, Wr2, dil_b, res_b, gTL,
        skip_w, skip_b, f1_w, f1_b, f2_w, f2_b, (float*)d_out);
}

// Round 9
// 73.313 us; speedup vs baseline: 1.6265x; 1.6265x over previous
//
#include <hip/hip_runtime.h>
#include <hip/hip_bf16.h>

// WaveNet single-output inference on MI355X — per-wave sparse-tree pyramid, v4.
// Only skip_sum[:, :, 8190] matters; dependency positions per layer form an
// arithmetic progression with stride dilation/2 (h_12 never needed).
// fuseA: one WAVE owns one chunk's whole in_conv + layers 0-5 pyramid
//        (96->95->47->23->11->5->2) in per-wave LDS — no data barriers;
//        per-layer weights staged once per block (2 barriers/layer).
// fuseB: one WAVE per batch: layers 6-11 + skip sum + f1/f2 head, no barriers.
// Numerics: r6-verified 3-term bf16 split (Ah.Bh + Ah.Bl + Al.Bh); H stored as
// packed u32 (h | lo<<16), fragments extracted with bit-ops on read.

typedef __attribute__((ext_vector_type(8))) short short8;
typedef __attribute__((ext_vector_type(4))) float f32x4;

#define TLAST 8190
#define BATCH 32
#define MFMA(A, B, C) __builtin_amdgcn_mfma_f32_16x16x32_bf16(A, B, C, 0, 0, 0)

__device__ inline ushort bf16hi(float v) {
    union { __hip_bfloat16 b; ushort u; } c;
    c.b = __float2bfloat16(v);
    return c.u;
}
__device__ inline uint packsplit(float v) {
    const ushort h = bf16hi(v);
    const float hf = __uint_as_float((uint)h << 16);
    const ushort l = bf16hi(v - hf);
    return (uint)h | ((uint)l << 16);
}
__device__ inline float unpacksum(uint u) {
    return __uint_as_float(u << 16) + __uint_as_float(u & 0xffff0000u);
}
__device__ inline int imin(int a, int b) { return a < b ? a : b; }
__device__ inline short8 mk8(uint a, uint b, uint c, uint d) {
    union { uint4 v; short8 s; } u; u.v = make_uint4(a, b, c, d); return u.s;
}
// 8 packed u32 (channels ascending) -> main frag (low halves) + corr (high)
__device__ inline void rdrow(const uint* p, short8& mh, short8& mc) {
    const uint4 q0 = *(const uint4*)p;
    const uint4 q1 = *(const uint4*)(p + 4);
    mh = mk8((q0.x & 0xffffu) | (q0.y << 16), (q0.z & 0xffffu) | (q0.w << 16),
             (q1.x & 0xffffu) | (q1.y << 16), (q1.z & 0xffffu) | (q1.w << 16));
    mc = mk8((q0.x >> 16) | (q0.y & 0xffff0000u), (q0.z >> 16) | (q0.w & 0xffff0000u),
             (q1.x >> 16) | (q1.y & 0xffff0000u), (q1.z >> 16) | (q1.w & 0xffff0000u));
}

// ---------------------------------------------------------------- weight prep
// Frag-major bf16 layout. dil element k = ic + 32*kt (kt = tap), lane = o*16+nl,
// frag (a,kt,nt): Wd[l*8192 + ((kt*4+nt)*2+a)*512 + lane*8 + (k&7)], a: 0=h 1=lo.
// res element k = ic, frag (a,nt): Wr[l*2048 + (nt*2+a)*512 + lane*8 + (k&7)].
__global__ __launch_bounds__(256) void wn_prep(
    const float* __restrict__ dil_w, const float* __restrict__ res_w,
    ushort* __restrict__ Wd, ushort* __restrict__ Wr)
{
    const int idx = blockIdx.x * 256 + threadIdx.x;
    if (idx < 12 * 4096) {
        const int l = idx >> 12, rem = idx & 4095, n = rem >> 6, k = rem & 63;
        const int kt = k >> 5, ic = k & 31, o = (k >> 3) & 3, r8 = k & 7;
        const int lane = o * 16 + (n & 15), nt = n >> 4;
        const float v = dil_w[((size_t)l * 64 + n) * 64 + 2 * ic + kt];
        const ushort h = bf16hi(v);
        const ushort lo = bf16hi(v - __uint_as_float((uint)h << 16));
        const int base = l * 8192 + ((kt * 4 + nt) * 2) * 512 + lane * 8 + r8;
        Wd[base] = h;
        Wd[base + 512] = lo;
    } else if (idx < 12 * 4096 + 12 * 1024) {
        const int j = idx - 12 * 4096;
        const int l = j >> 10, rem = j & 1023, n = rem >> 5, k = rem & 31;
        const int o = k >> 3, r8 = k & 7;
        const int lane = o * 16 + (n & 15), nt = n >> 4;
        const float v = res_w[j];
        const ushort h = bf16hi(v);
        const ushort lo = bf16hi(v - __uint_as_float((uint)h << 16));
        const int base = l * 2048 + (nt * 2) * 512 + lane * 8 + r8;
        Wr[base] = h;
        Wr[base + 512] = lo;
    }
}

// ---------------------------------------------------------------- phase A
// Grid (8, BATCH), 256 thr. Wave w owns chunk cc = bx*4+w: h6 at t6a, t6a+32.
// Per-wave LDS blob: ping 96*36, pong 48*36, sG 16*36 (u32, stride 36).
// Layer l=0 runs in-place in ping (reads hoisted before stores).
__global__ __launch_bounds__(256, 1) void wn_fuseA(
    const float* __restrict__ x, const float* __restrict__ in_w,
    const float* __restrict__ in_b,
    const ushort* __restrict__ Wd, const ushort* __restrict__ Wr,
    const float* __restrict__ dil_b, const float* __restrict__ res_b,
    uint* __restrict__ c6, float* __restrict__ gTL)
{
    __shared__ __align__(16) uint blob[4][5760];
    __shared__ __align__(16) ushort sWd[8192];
    __shared__ __align__(16) ushort sWr[2048];

    const int tid = threadIdx.x, lane = tid & 63, w = tid >> 6;
    const int nl = lane & 15, o = lane >> 4;
    const int cc = blockIdx.x * 4 + w, b = blockIdx.y;
    uint* ping = blob[w];
    uint* pong = blob[w] + 3456;
    uint* sG   = blob[w] + 5184;
    float* xs  = (float*)(blob[w] + 3456);     // 1920 f, overlays pong+sG

    const int t6a = 6174 + cc * 64, a0 = t6a - 31;
    const short8 z8 = {0, 0, 0, 0, 0, 0, 0, 0};

    // ---- stage x (96 pos x 16 ch fp32), per wave
    for (int i = lane; i < 384; i += 64) {
        const int p = i >> 2, c4 = (i & 3) * 4;
        const int t = a0 + p;
        float4 v = make_float4(0.f, 0.f, 0.f, 0.f);
        if (t <= 8191) v = *(const float4*)&x[((size_t)b * 8192 + t) * 16 + c4];
        *(float4*)&xs[p * 20 + c4] = v;
    }

    // ---- in_conv -> ping (packed)
    {
        const int c = lane & 31, pg = lane >> 5;
        float wr[16];
        #pragma unroll
        for (int f = 0; f < 16; ++f) wr[f] = in_w[c * 16 + f];
        const float bias = in_b[c];
        for (int q = 0; q < 48; ++q) {
            const int p = pg + 2 * q;
            float acc = bias;
            #pragma unroll
            for (int f4 = 0; f4 < 4; ++f4) {
                const float4 xv = *(const float4*)&xs[p * 20 + f4 * 4];
                acc += wr[f4*4]*xv.x + wr[f4*4+1]*xv.y
                     + wr[f4*4+2]*xv.z + wr[f4*4+3]*xv.w;
            }
            ping[p * 36 + c] = packsplit(acc);
        }
    }

    for (int l = 0; l < 6; ++l) {
        const uint* Hi = (l == 0 || (l & 1)) ? ping : pong;
        uint*       Ho = (l & 1) ? pong : ping;
        const int nIn  = (l == 0) ? 96 : (192 >> l) - 1;
        const int nOut = (192 >> (l + 1)) - 1;      // 95,47,23,11,5,2
        const int nT   = (nOut + 15) >> 4;
        const int sO   = 1 << l;
        const int aO   = a0 + sO - 1;
        const int bOff = (l == 0) ? 1 : (sO >> 1);
        const int rmx  = (l == 0) ? 8191 : TLAST;

        __syncthreads();    // all waves done with previous layer's weight LDS
        {
            const uint4* gd = (const uint4*)(Wd + (size_t)l * 8192);
            for (int i = tid; i < 1024; i += 256) ((uint4*)sWd)[i] = gd[i];
            ((uint4*)sWr)[tid] = ((const uint4*)(Wr + (size_t)l * 2048))[tid];
        }
        __syncthreads();

        // ---- hoist weight fragments (lane-linear ds_read_b128)
        short8 Bh[4][2], Bl[4][2], Rh[2], Rl[2];
        #pragma unroll
        for (int nt = 0; nt < 4; ++nt)
            #pragma unroll
            for (int kt = 0; kt < 2; ++kt) {
                const int base = ((kt * 4 + nt) * 2) * 512 + lane * 8;
                Bh[nt][kt] = *(const short8*)&sWd[base];
                Bl[nt][kt] = *(const short8*)&sWd[base + 512];
            }
        #pragma unroll
        for (int nt = 0; nt < 2; ++nt) {
            const int base = (nt * 2) * 512 + lane * 8;
            Rh[nt] = *(const short8*)&sWr[base];
            Rl[nt] = *(const short8*)&sWr[base + 512];
        }
        float dbg[2], dbf[2], rbv[2];
        #pragma unroll
        for (int nt = 0; nt < 2; ++nt) {
            dbg[nt] = dil_b[l * 64 + nl + 16 * nt];
            dbf[nt] = dil_b[l * 64 + nl + 16 * nt + 32];
            rbv[nt] = res_b[l * 32 + nl + 16 * nt];
        }

        for (int tt = 0; tt < nT; ++tt) {
            const int joF = tt * 16 + nl;
            const int j0 = imin((l == 0) ? joF : 2 * joF, nIn - 1);
            const int j1 = imin((l == 0) ? joF + 1 : 2 * joF + 2, nIn - 1);
            const bool zB = (aO + joF * sO + bOff) > rmx;

            short8 Ah[2], Al[2];
            rdrow(Hi + j0 * 36 + 8 * o, Ah[0], Al[0]);
            if (zB) { Ah[1] = z8; Al[1] = z8; }
            else    rdrow(Hi + j1 * 36 + 8 * o, Ah[1], Al[1]);

            // gate/filt GEMM: 24 MFMAs
            f32x4 acc[4] = {{0,0,0,0},{0,0,0,0},{0,0,0,0},{0,0,0,0}};
            #pragma unroll
            for (int kt = 0; kt < 2; ++kt)
                #pragma unroll
                for (int nt = 0; nt < 4; ++nt) {
                    acc[nt] = MFMA(Ah[kt], Bh[nt][kt], acc[nt]);
                    acc[nt] = MFMA(Ah[kt], Bl[nt][kt], acc[nt]);
                    acc[nt] = MFMA(Al[kt], Bh[nt][kt], acc[nt]);
                }

            // activation + packed G + gTL capture
            #pragma unroll
            for (int nt = 0; nt < 2; ++nt)
                #pragma unroll
                for (int r = 0; r < 4; ++r) {
                    const float gate = acc[nt][r]     + dbg[nt];
                    const float filt = acc[nt + 2][r] + dbf[nt];
                    const float sg = 1.f / (1.f + __expf(-gate));
                    const float th = 2.f / (1.f + __expf(-2.f * filt)) - 1.f;
                    const float g  = th * sg;
                    const int ml = 4 * o + r, n = nl + 16 * nt;
                    sG[ml * 36 + n] = packsplit(g);
                    const int joG = tt * 16 + ml;
                    if (joG < nOut && (aO + joG * sO) == TLAST)
                        gTL[((size_t)l * BATCH + b) * 32 + n] = g;
                }

            // res GEMM: 6 MFMAs (same-wave sG)
            short8 gh, gl;
            rdrow(sG + nl * 36 + 8 * o, gh, gl);
            f32x4 accR[2] = {{0,0,0,0},{0,0,0,0}};
            #pragma unroll
            for (int nt = 0; nt < 2; ++nt) {
                accR[nt] = MFMA(gh, Rh[nt], accR[nt]);
                accR[nt] = MFMA(gh, Rl[nt], accR[nt]);
                accR[nt] = MFMA(gl, Rh[nt], accR[nt]);
            }

            // epilogue: hoist ALL residual reads before ANY store (l=0 in-place)
            float resv[2][4];
            #pragma unroll
            for (int nt = 0; nt < 2; ++nt)
                #pragma unroll
                for (int r = 0; r < 4; ++r) {
                    const int joE = tt * 16 + 4 * o + r;
                    const int jres = imin((l == 0) ? joE + 1 : 2 * joE + 1, nIn - 1);
                    resv[nt][r] = unpacksum(Hi[jres * 36 + nl + 16 * nt]);
                }
            #pragma unroll
            for (int nt = 0; nt < 2; ++nt)
                #pragma unroll
                for (int r = 0; r < 4; ++r) {
                    const int joE = tt * 16 + 4 * o + r;
                    const int n = nl + 16 * nt;
                    const float hv = accR[nt][r] + rbv[nt] + resv[nt][r];
                    const uint pk = packsplit(hv);
                    Ho[joE * 36 + n] = pk;
                    if (l == 5 && joE < 2)
                        c6[((size_t)b * 64 + cc * 2 + joE) * 32 + n] = pk;
                }
        }
    }
}

// ---------------------------------------------------------------- phase B
// Grid 8, 256 thr: wave w owns batch b = bx*4+w. Layers 6-11 + head, 0 barriers.
__global__ __launch_bounds__(256, 1) void wn_fuseB(
    const uint* __restrict__ c6,
    const ushort* __restrict__ Wd, const ushort* __restrict__ Wr,
    const float* __restrict__ dil_b, const float* __restrict__ res_b,
    const float* __restrict__ gTL,
    const float* __restrict__ sw, const float* __restrict__ sb,
    const float* __restrict__ f1w, const float* __restrict__ f1b,
    const float* __restrict__ f2w, const float* __restrict__ f2b,
    float* __restrict__ out)
{
    __shared__ __align__(16) uint blob[4][4032];   // HA 64*36 | HB 32*36 | sG 16*36
    __shared__ float fsc[4][256];                  // gcap 192 | hd 64

    const int tid = threadIdx.x, lane = tid & 63, w = tid >> 6;
    const int nl = lane & 15, o = lane >> 4;
    const int b = blockIdx.x * 4 + w;
    uint* HA = blob[w];
    uint* HB = blob[w] + 2304;
    uint* sG = blob[w] + 3456;
    float* gcap = fsc[w];
    float* hd   = fsc[w] + 192;
    const short8 z8 = {0, 0, 0, 0, 0, 0, 0, 0};

    // ---- stage this batch's 64 compact h6 rows
    for (int i = lane; i < 512; i += 64) {
        const int row = i >> 3, c4 = (i & 7) * 4;
        *(uint4*)&HA[row * 36 + c4] = *(const uint4*)&c6[((size_t)b * 64 + row) * 32 + c4];
    }

    for (int ll = 0; ll < 6; ++ll) {
        const int l = ll + 6;
        const uint* Hi = (ll & 1) ? HB : HA;
        uint*       Ho = (ll & 1) ? HA : HB;
        const int nIn  = 64 >> ll;
        const int nOut = 32 >> ll;
        const int nT   = (nOut + 15) >> 4;
        const int sO   = 64 << ll;
        const int aO   = 6142 + sO;
        const int bOff = sO >> 1;

        // hoist weight fragments straight from frag-major global (coalesced)
        const ushort* pd = Wd + (size_t)l * 8192;
        const ushort* pr = Wr + (size_t)l * 2048;
        short8 Bh[4][2], Bl[4][2], Rh[2], Rl[2];
        #pragma unroll
        for (int nt = 0; nt < 4; ++nt)
            #pragma unroll
            for (int kt = 0; kt < 2; ++kt) {
                const int base = ((kt * 4 + nt) * 2) * 512 + lane * 8;
                Bh[nt][kt] = *(const short8*)&pd[base];
                Bl[nt][kt] = *(const short8*)&pd[base + 512];
            }
        #pragma unroll
        for (int nt = 0; nt < 2; ++nt) {
            const int base = (nt * 2) * 512 + lane * 8;
            Rh[nt] = *(const short8*)&pr[base];
            Rl[nt] = *(const short8*)&pr[base + 512];
        }
        float dbg[2], dbf[2], rbv[2];
        #pragma unroll
        for (int nt = 0; nt < 2; ++nt) {
            dbg[nt] = dil_b[l * 64 + nl + 16 * nt];
            dbf[nt] = dil_b[l * 64 + nl + 16 * nt + 32];
            rbv[nt] = res_b[l * 32 + nl + 16 * nt];
        }

        for (int tt = 0; tt < nT; ++tt) {
            const int joF = tt * 16 + nl;
            const int j0 = imin(2 * joF, nIn - 1);
            const int j1 = imin(2 * joF + 2, nIn - 1);
            const bool zB = (aO + joF * sO + bOff) > TLAST;

            short8 Ah[2], Al[2];
            rdrow(Hi + j0 * 36 + 8 * o, Ah[0], Al[0]);
            if (zB) { Ah[1] = z8; Al[1] = z8; }
            else    rdrow(Hi + j1 * 36 + 8 * o, Ah[1], Al[1]);

            f32x4 acc[4] = {{0,0,0,0},{0,0,0,0},{0,0,0,0},{0,0,0,0}};
            #pragma unroll
            for (int kt = 0; kt < 2; ++kt)
                #pragma unroll
                for (int nt = 0; nt < 4; ++nt) {
                    acc[nt] = MFMA(Ah[kt], Bh[nt][kt], acc[nt]);
                    acc[nt] = MFMA(Ah[kt], Bl[nt][kt], acc[nt]);
                    acc[nt] = MFMA(Al[kt], Bh[nt][kt], acc[nt]);
                }

            #pragma unroll
            for (int nt = 0; nt < 2; ++nt)
                #pragma unroll
                for (int r = 0; r < 4; ++r) {
                    const float gate = acc[nt][r]     + dbg[nt];
                    const float filt = acc[nt + 2][r] + dbf[nt];
                    const float sg = 1.f / (1.f + __expf(-gate));
                    const float th = 2.f / (1.f + __expf(-2.f * filt)) - 1.f;
                    const float g  = th * sg;
                    const int ml = 4 * o + r, n = nl + 16 * nt;
                    sG[ml * 36 + n] = packsplit(g);
                    const int joG = tt * 16 + ml;
                    if (joG < nOut && (aO + joG * sO) == TLAST)
                        gcap[ll * 32 + n] = g;
                }

            if (ll < 5) {
                short8 gh, gl;
                rdrow(sG + nl * 36 + 8 * o, gh, gl);
                f32x4 accR[2] = {{0,0,0,0},{0,0,0,0}};
                #pragma unroll
                for (int nt = 0; nt < 2; ++nt) {
                    accR[nt] = MFMA(gh, Rh[nt], accR[nt]);
                    accR[nt] = MFMA(gh, Rl[nt], accR[nt]);
                    accR[nt] = MFMA(gl, Rh[nt], accR[nt]);
                }
                #pragma unroll
                for (int nt = 0; nt < 2; ++nt)
                    #pragma unroll
                    for (int r = 0; r < 4; ++r) {
                        const int joE = tt * 16 + 4 * o + r;
                        const int jres = imin(2 * joE + 1, nIn - 1);
                        const int n = nl + 16 * nt;
                        const float resv = unpacksum(Hi[jres * 36 + n]);
                        Ho[joE * 36 + n] = packsplit(accR[nt][r] + rbv[nt] + resv);
                    }
            }
        }
    }

    // ---- head (same wave): relu(skip_sum) -> f1 -> relu -> f2
    if (lane < 32) {
        const int c = lane;
        float acc = 0.f;
        for (int l2 = 0; l2 < 12; ++l2) {
            float a = sb[l2 * 32 + c];
            const float* swr = sw + l2 * 1024 + c * 32;
            if (l2 < 6) {
                const float* gv = gTL + ((size_t)l2 * BATCH + b) * 32;
                #pragma unroll
                for (int ic = 0; ic < 32; ++ic) a += swr[ic] * gv[ic];
            } else {
                const float* gv = gcap + (l2 - 6) * 32;
                #pragma unroll
                for (int ic = 0; ic < 32; ++ic) a += swr[ic] * gv[ic];
            }
            acc += a;
        }
        hd[c] = fmaxf(acc, 0.f);
    }
    if (lane < 32) {
        float z = f1b[lane];
        #pragma unroll
        for (int ic = 0; ic < 32; ++ic) z += f1w[lane * 32 + ic] * hd[ic];
        hd[32 + lane] = fmaxf(z, 0.f);
    }
    if (lane == 0) {
        float o2 = f2b[0];
        #pragma unroll
        for (int ic = 0; ic < 32; ++ic) o2 += f2w[ic] * hd[32 + ic];
        out[b] = o2;
    }
}

// ---------------------------------------------------------------- launch
extern "C" void kernel_launch(void* const* d_in, const int* in_sizes, int n_in,
                              void* d_out, int out_size, void* d_ws, size_t ws_size,
                              hipStream_t stream)
{
    const float* x      = (const float*)d_in[0];
    const float* in_w   = (const float*)d_in[1];
    const float* in_b   = (const float*)d_in[2];
    const float* dil_w  = (const float*)d_in[3];
    const float* dil_b  = (const float*)d_in[4];
    const float* skip_w = (const float*)d_in[5];
    const float* skip_b = (const float*)d_in[6];
    const float* res_w  = (const float*)d_in[7];
    const float* res_b  = (const float*)d_in[8];
    const float* f1_w   = (const float*)d_in[9];
    const float* f1_b   = (const float*)d_in[10];
    const float* f2_w   = (const float*)d_in[11];
    const float* f2_b   = (const float*)d_in[12];

    char* p = (char*)d_ws;
    ushort* Wd = (ushort*)p; p += 12 * 8192 * 2;
    ushort* Wr = (ushort*)p; p += 12 * 2048 * 2;
    uint*   c6 = (uint*)p;   p += 32 * 64 * 32 * 4;
    float* gTL = (float*)p;  // [12][32][32]

    wn_prep<<<dim3(240), dim3(256), 0, stream>>>(dil_w, res_w, Wd, Wr);

    wn_fuseA<<<dim3(8, BATCH), dim3(256), 0, stream>>>(
        x, in_w, in_b, Wd, Wr, dil_b, res_b, c6, gTL);

    wn_fuseB<<<dim3(8), dim3(256), 0, stream>>>(
        c6, Wd, Wr, dil_b, res_b, gTL,
        skip_w, skip_b, f1_w, f1_b, f2_w, f2_b, (float*)d_out);
}